// Round 6
// baseline (316.236 us; speedup 1.0000x reference)
//
#include <hip/hip_runtime.h>
#include <hip/hip_bf16.h>
#include <stdint.h>
#include <math.h>

#define B_ 4
#define T_ 2048
#define E_ 1024
#define H_ 16
#define D_ 64

typedef __attribute__((ext_vector_type(8))) short short8;
typedef __attribute__((ext_vector_type(4))) float f32x4;

#define MFMA_BF16(a, b, c) __builtin_amdgcn_mfma_f32_16x16x32_bf16((a), (b), (c), 0, 0, 0)

__device__ __forceinline__ unsigned short f2bf(float f) {
  union { float f; unsigned u; } v; v.f = f;
  unsigned r = v.u + 0x7FFFu + ((v.u >> 16) & 1u);  // RNE
  return (unsigned short)(r >> 16);
}

#define GLOAD_LDS16(g, l)                                                        \
  __builtin_amdgcn_global_load_lds((const __attribute__((address_space(1))) void*)(g), \
                                   (__attribute__((address_space(3))) void*)(l), 16, 0, 0)

// ---------------- fp32 -> bf16 convert (vectorized) ----------------
__global__ __launch_bounds__(256) void cvt_f32_bf16(const float* __restrict__ in,
                                                    unsigned short* __restrict__ out,
                                                    int n8) {
  int i = blockIdx.x * blockDim.x + threadIdx.x;
  if (i >= n8) return;
  const float4* p = (const float4*)(in + (size_t)i * 8);
  float4 a = p[0], b = p[1];
  short8 r;
  r[0] = (short)f2bf(a.x); r[1] = (short)f2bf(a.y);
  r[2] = (short)f2bf(a.z); r[3] = (short)f2bf(a.w);
  r[4] = (short)f2bf(b.x); r[5] = (short)f2bf(b.y);
  r[6] = (short)f2bf(b.z); r[7] = (short)f2bf(b.w);
  *(short8*)(out + (size_t)i * 8) = r;
}

// 4 weight matrices in one launch (dest regions contiguous in ws)
__global__ __launch_bounds__(256) void cvt_w4(const float* __restrict__ w0,
                                              const float* __restrict__ w1,
                                              const float* __restrict__ w2,
                                              const float* __restrict__ w3,
                                              unsigned short* __restrict__ out) {
  int i = blockIdx.x * blockDim.x + threadIdx.x;  // one per 8 elems
  int which = i >> 17;                            // WE/8 = 2^17
  int off = i & 131071;
  const float* src = (which == 0) ? w0 : (which == 1) ? w1 : (which == 2) ? w2 : w3;
  const float4* p = (const float4*)(src + (size_t)off * 8);
  float4 a = p[0], b = p[1];
  short8 r;
  r[0] = (short)f2bf(a.x); r[1] = (short)f2bf(a.y);
  r[2] = (short)f2bf(a.z); r[3] = (short)f2bf(a.w);
  r[4] = (short)f2bf(b.x); r[5] = (short)f2bf(b.y);
  r[6] = (short)f2bf(b.z); r[7] = (short)f2bf(b.w);
  *(short8*)(out + ((size_t)which << 20) + (size_t)off * 8) = r;
}

// ---------------- fused QKV GEMM: C = x * W^T for W in {Wq,Wk,Wv} -------------
// sel 0/1 (Q,K): write bf16 [B*H][T][D]. sel 2 (V): write bf16 TRANSPOSED
// [B*H][D][T] (same scattered-2B store cost; saves a transpose pass).
__global__ __launch_bounds__(256) void gemm_qkv(const unsigned short* __restrict__ A,
                                                const unsigned short* __restrict__ Wq,
                                                const unsigned short* __restrict__ Wk,
                                                const unsigned short* __restrict__ Wv,
                                                unsigned short* __restrict__ Qo,
                                                unsigned short* __restrict__ Ko,
                                                unsigned short* __restrict__ Vo) {
  __shared__ __align__(16) unsigned short Ab[128 * 64];
  __shared__ __align__(16) unsigned short Bb[128 * 64];
  const int K = E_;
  const int tid = threadIdx.x;
  const int wid = tid >> 6;
  const int lr = tid & 15;
  const int lk = (tid >> 4) & 3;
  const int wr = wid >> 1, wc = wid & 1;
  const int m0 = blockIdx.x * 128;
  const int sel = blockIdx.y >> 3;
  const int n0 = (blockIdx.y & 7) * 128;
  const unsigned short* Bm = (sel == 0) ? Wq : (sel == 1) ? Wk : Wv;
  unsigned short* outp = (sel == 0) ? Qo : (sel == 1) ? Ko : Vo;

  f32x4 acc[4][4] = {};

  for (int k0 = 0; k0 < K; k0 += 64) {
    __syncthreads();
#pragma unroll
    for (int pass = 0; pass < 4; ++pass) {
      int chunk = pass * 256 + tid;
      int row = chunk >> 3, inner = chunk & 7;
      const unsigned short* ga = A + (size_t)(m0 + row) * K + k0 + inner * 8;
      const unsigned short* gb = Bm + (size_t)(n0 + row) * K + k0 + inner * 8;
      unsigned short* la = Ab + (size_t)(pass * 256 + wid * 64) * 8;
      unsigned short* lb = Bb + (size_t)(pass * 256 + wid * 64) * 8;
      GLOAD_LDS16(ga, la);
      GLOAD_LDS16(gb, lb);
    }
    __syncthreads();
#pragma unroll
    for (int kk = 0; kk < 2; ++kk) {
      short8 af[4], bf[4];
#pragma unroll
      for (int mi = 0; mi < 4; ++mi)
        af[mi] = *(const short8*)&Ab[(wr * 64 + mi * 16 + lr) * 64 + kk * 32 + lk * 8];
#pragma unroll
      for (int ni = 0; ni < 4; ++ni)
        bf[ni] = *(const short8*)&Bb[(wc * 64 + ni * 16 + lr) * 64 + kk * 32 + lk * 8];
#pragma unroll
      for (int mi = 0; mi < 4; ++mi)
#pragma unroll
        for (int ni = 0; ni < 4; ++ni)
          acc[mi][ni] = MFMA_BF16(af[mi], bf[ni], acc[mi][ni]);
    }
  }

#pragma unroll
  for (int mi = 0; mi < 4; ++mi)
#pragma unroll
    for (int ni = 0; ni < 4; ++ni)
#pragma unroll
      for (int r = 0; r < 4; ++r) {
        int row = m0 + wr * 64 + mi * 16 + lk * 4 + r;
        int col = n0 + wc * 64 + ni * 16 + lr;
        int b = row >> 11, t = row & (T_ - 1), h = col >> 6, d = col & (D_ - 1);
        unsigned short v = f2bf(acc[mi][ni][r]);
        if (sel == 2)
          outp[(((size_t)(b * H_ + h)) * D_ + d) * T_ + t] = v;   // [BH][D][T]
        else
          outp[(((size_t)(b * H_ + h)) * T_ + t) * D_ + d] = v;   // [BH][T][D]
      }
}

// ---------------- out-proj GEMM: fp32 out + bias ----------------
__global__ __launch_bounds__(256) void gemm_out(const unsigned short* __restrict__ A,
                                                const unsigned short* __restrict__ Bm,
                                                float* __restrict__ outp,
                                                const float* __restrict__ bias,
                                                int M, int N, int K) {
  __shared__ __align__(16) unsigned short Ab[128 * 64];
  __shared__ __align__(16) unsigned short Bb[128 * 64];
  const int tid = threadIdx.x;
  const int wid = tid >> 6;
  const int lr = tid & 15;
  const int lk = (tid >> 4) & 3;
  const int wr = wid >> 1, wc = wid & 1;
  const int m0 = blockIdx.x * 128, n0 = blockIdx.y * 128;

  f32x4 acc[4][4] = {};

  for (int k0 = 0; k0 < K; k0 += 64) {
    __syncthreads();
#pragma unroll
    for (int pass = 0; pass < 4; ++pass) {
      int chunk = pass * 256 + tid;
      int row = chunk >> 3, inner = chunk & 7;
      const unsigned short* ga = A + (size_t)(m0 + row) * K + k0 + inner * 8;
      const unsigned short* gb = Bm + (size_t)(n0 + row) * K + k0 + inner * 8;
      unsigned short* la = Ab + (size_t)(pass * 256 + wid * 64) * 8;
      unsigned short* lb = Bb + (size_t)(pass * 256 + wid * 64) * 8;
      GLOAD_LDS16(ga, la);
      GLOAD_LDS16(gb, lb);
    }
    __syncthreads();
#pragma unroll
    for (int kk = 0; kk < 2; ++kk) {
      short8 af[4], bf[4];
#pragma unroll
      for (int mi = 0; mi < 4; ++mi)
        af[mi] = *(const short8*)&Ab[(wr * 64 + mi * 16 + lr) * 64 + kk * 32 + lk * 8];
#pragma unroll
      for (int ni = 0; ni < 4; ++ni)
        bf[ni] = *(const short8*)&Bb[(wc * 64 + ni * 16 + lr) * 64 + kk * 32 + lk * 8];
#pragma unroll
      for (int mi = 0; mi < 4; ++mi)
#pragma unroll
        for (int ni = 0; ni < 4; ++ni)
          acc[mi][ni] = MFMA_BF16(af[mi], bf[ni], acc[mi][ni]);
    }
  }

#pragma unroll
  for (int mi = 0; mi < 4; ++mi)
#pragma unroll
    for (int ni = 0; ni < 4; ++ni)
#pragma unroll
      for (int r = 0; r < 4; ++r) {
        int row = m0 + wr * 64 + mi * 16 + lk * 4 + r;
        int col = n0 + wc * 64 + ni * 16 + lr;
        outp[(size_t)row * N + col] = acc[mi][ni][r] + bias[col];
      }
}

// ---------------- fused causal flash attention (LDS-free) ----------------
// 4096 blocks x 64 thr; one 32-row q-chunk per wave. No LDS, no barriers.
// S^T = mfma(K,Q): lane (lr,lk) holds P[q=lr][kv=16n+lk*4+r] — which IS the
// PV A-fragment under k-slot map sigma(lk,j)=16*(2h+(j>>2))+lk*4+(j&3).
// V is loaded with the SAME sigma (two b64 per fragment), so PV needs zero
// cross-lane data movement. P packs in-register via cvt_pk pairs.
__global__ __launch_bounds__(64) void attn_fused(const unsigned short* __restrict__ Q,
                                                 const unsigned short* __restrict__ K,
                                                 const unsigned short* __restrict__ VT,
                                                 unsigned short* __restrict__ ctx) {
  const int tid = threadIdx.x;
  const int lane = tid & 63;
  const int lr = lane & 15;
  const int lk = lane >> 4;

  // XCD swizzle: 8 heads/XCD; heaviest chunks dispatched first.
  const int bid = blockIdx.x;
  const int xcd = bid & 7;
  const int p = bid >> 3;           // 0..511 per XCD
  const int chunk = 63 - (p >> 3);  // heavy first
  const int bh = xcd * 8 + (p & 7);
  const int q0 = chunk * 32;

  const unsigned short* Qh = Q + (size_t)bh * T_ * D_;
  const unsigned short* Kh = K + (size_t)bh * T_ * D_;
  const unsigned short* Vh = VT + (size_t)bh * T_ * D_;  // [D][T]

  const float SC = 0.125f * 1.44269504089f;  // 1/sqrt(D) * log2(e)

  short8 vones;
#pragma unroll
  for (int j = 0; j < 8; ++j) vones[j] = (short)0x3F80;  // bf16 1.0

  // Q as B-operand: col=q=lr, k=d
  short8 qf[2][2];
#pragma unroll
  for (int a = 0; a < 2; ++a)
#pragma unroll
    for (int kb = 0; kb < 2; ++kb)
      qf[a][kb] = *(const short8*)&Qh[(size_t)(q0 + a * 16 + lr) * D_ + kb * 32 + lk * 8];

  f32x4 o[2][4] = {};
  f32x4 lsum[2] = {};
  float mrun[2] = {-1e30f, -1e30f};

  const int nt = (q0 >> 6) + 1;
  const int ql0 = (q0 & 63);  // q-local base within diag tile

  for (int kvt = 0; kvt < nt; ++kvt) {
    const unsigned short* Kt = Kh + (size_t)kvt * 64 * D_;
    const unsigned short* Vtt = Vh + (size_t)kvt * 64;

    // K fragments (QK waits on these)
    short8 kf[2][4];
#pragma unroll
    for (int kb = 0; kb < 2; ++kb)
#pragma unroll
      for (int n = 0; n < 4; ++n)
        kf[kb][n] = *(const short8*)&Kt[(size_t)(n * 16 + lr) * D_ + kb * 32 + lk * 8];

    // V fragments with sigma k-slot layout: slot j<4 -> kv=32h+lk*4+j,
    // slot j>=4 -> kv=32h+16+lk*4+(j-4). Two b64 loads per fragment.
    short8 vreg[2][4];
#pragma unroll
    for (int h = 0; h < 2; ++h)
#pragma unroll
      for (int nd = 0; nd < 4; ++nd) {
        const unsigned short* vp = &Vtt[(size_t)(nd * 16 + lr) * T_ + h * 32 + lk * 4];
        *(uint2*)&vreg[h][nd] = *(const uint2*)vp;
        *((uint2*)&vreg[h][nd] + 1) = *(const uint2*)(vp + 16);
      }

    // S^T = K Q^T : lane holds q=lr, kv = 16n + lk*4 + r
    f32x4 st[2][4] = {};
#pragma unroll
    for (int kb = 0; kb < 2; ++kb)
#pragma unroll
      for (int a = 0; a < 2; ++a)
#pragma unroll
        for (int n = 0; n < 4; ++n)
          st[a][n] = MFMA_BF16(kf[kb][n], qf[a][kb], st[a][n]);

    if (kvt == nt - 1) {  // diagonal tile: mask kv_local > q_local
#pragma unroll
      for (int a = 0; a < 2; ++a)
#pragma unroll
        for (int n = 0; n < 4; ++n)
#pragma unroll
          for (int r = 0; r < 4; ++r)
            if (n * 16 + lk * 4 + r > ql0 + a * 16 + lr) st[a][n][r] = -3e38f;
    }

    // row max (in-lane tree + 2 shuffles)
    float pm[2];
#pragma unroll
    for (int a = 0; a < 2; ++a) {
      float m0 = fmaxf(fmaxf(st[a][0][0], st[a][1][0]), fmaxf(st[a][2][0], st[a][3][0]));
      float m1 = fmaxf(fmaxf(st[a][0][1], st[a][1][1]), fmaxf(st[a][2][1], st[a][3][1]));
      float m2 = fmaxf(fmaxf(st[a][0][2], st[a][1][2]), fmaxf(st[a][2][2], st[a][3][2]));
      float m3 = fmaxf(fmaxf(st[a][0][3], st[a][1][3]), fmaxf(st[a][2][3], st[a][3][3]));
      float mx = fmaxf(fmaxf(m0, m1), fmaxf(m2, m3));
      mx = fmaxf(mx, __shfl_xor(mx, 16));
      mx = fmaxf(mx, __shfl_xor(mx, 32));
      pm[a] = mx * SC;
    }
    float need = fmaxf(pm[0] - mrun[0], pm[1] - mrun[1]);

    if (__any(need > 8.f)) {  // defer-max rescale (rare)
#pragma unroll
      for (int a = 0; a < 2; ++a) {
        float mnew = fmaxf(mrun[a], pm[a]);
        float sc = exp2f(mrun[a] - mnew);
        mrun[a] = mnew;
#pragma unroll
        for (int r = 0; r < 4; ++r) {
          float sco = __shfl(sc, (lane & 48) | (lk * 4 + r));
          lsum[a][r] *= sco;
#pragma unroll
          for (int nd = 0; nd < 4; ++nd) o[a][nd][r] *= sco;
        }
      }
    }

    // P = exp2(S*SC - m): pack in-register to A-fragments (no LDS!)
    // pf[a][h] dword d: d=0 -> (n=2h, r=0,1), d=1 -> (2h, r=2,3),
    //                   d=2 -> (2h+1, r=0,1), d=3 -> (2h+1, r=2,3)
    short8 pf[2][2];
#pragma unroll
    for (int a = 0; a < 2; ++a) {
      f32x4 pt[4];
#pragma unroll
      for (int n = 0; n < 4; ++n)
#pragma unroll
        for (int r = 0; r < 4; ++r)
          pt[n][r] = exp2f(fmaf(st[a][n][r], SC, -mrun[a]));
#pragma unroll
      for (int h = 0; h < 2; ++h) {
        float2 x01, x23, y01, y23;
        x01.x = pt[2 * h][0];  x01.y = pt[2 * h][1];
        x23.x = pt[2 * h][2];  x23.y = pt[2 * h][3];
        y01.x = pt[2 * h + 1][0]; y01.y = pt[2 * h + 1][1];
        y23.x = pt[2 * h + 1][2]; y23.y = pt[2 * h + 1][3];
        __hip_bfloat162 b0 = __float22bfloat162_rn(x01);
        __hip_bfloat162 b1 = __float22bfloat162_rn(x23);
        __hip_bfloat162 b2 = __float22bfloat162_rn(y01);
        __hip_bfloat162 b3 = __float22bfloat162_rn(y23);
        unsigned* w = (unsigned*)&pf[a][h];
        w[0] = *(unsigned*)&b0;
        w[1] = *(unsigned*)&b1;
        w[2] = *(unsigned*)&b2;
        w[3] = *(unsigned*)&b3;
      }
    }

    // O += P V ; lsum += P * ones  (pure register MFMA)
#pragma unroll
    for (int h = 0; h < 2; ++h) {
#pragma unroll
      for (int nd = 0; nd < 4; ++nd) {
        o[0][nd] = MFMA_BF16(pf[0][h], vreg[h][nd], o[0][nd]);
        o[1][nd] = MFMA_BF16(pf[1][h], vreg[h][nd], o[1][nd]);
      }
      lsum[0] = MFMA_BF16(pf[0][h], vones, lsum[0]);
      lsum[1] = MFMA_BF16(pf[1][h], vones, lsum[1]);
    }
  }

  const int b = bh >> 4, h2 = bh & 15;
#pragma unroll
  for (int a = 0; a < 2; ++a)
#pragma unroll
    for (int r = 0; r < 4; ++r) {
      float inv = 1.0f / lsum[a][r];
      int t = q0 + a * 16 + lk * 4 + r;
#pragma unroll
      for (int nd = 0; nd < 4; ++nd)
        ctx[((size_t)b * T_ + t) * E_ + h2 * D_ + nd * 16 + lr] = f2bf(o[a][nd][r] * inv);
    }
}

// ---------------- launcher ----------------
extern "C" void kernel_launch(void* const* d_in, const int* in_sizes, int n_in,
                              void* d_out, int out_size, void* d_ws, size_t ws_size,
                              hipStream_t stream) {
  const float* x    = (const float*)d_in[0];
  const float* Wq   = (const float*)d_in[1];
  const float* Wk   = (const float*)d_in[2];
  const float* Wv   = (const float*)d_in[3];
  const float* Wout = (const float*)d_in[4];
  const float* bout = (const float*)d_in[5];
  float* out = (float*)d_out;

  const size_t MT = (size_t)B_ * T_;      // 8192
  const size_t XE = MT * E_;              // 8,388,608
  const size_t WE = (size_t)E_ * E_;      // 1,048,576

  size_t need = (XE * 5 + WE * 4) * sizeof(unsigned short);
  if (ws_size < need) return;

  unsigned short* xb  = (unsigned short*)d_ws;
  unsigned short* wqb = xb + XE;
  unsigned short* wkb = wqb + WE;
  unsigned short* wvb = wkb + WE;
  unsigned short* wob = wvb + WE;
  unsigned short* Qb  = wob + WE;
  unsigned short* Kb  = Qb + XE;
  unsigned short* VTb = Kb + XE;
  unsigned short* ctx = VTb + XE;

  cvt_f32_bf16<<<(int)(XE / 8 / 256), 256, 0, stream>>>(x, xb, (int)(XE / 8));
  cvt_w4<<<2048, 256, 0, stream>>>(Wq, Wk, Wv, Wout, wqb);

  gemm_qkv<<<dim3(MT / 128, 24), 256, 0, stream>>>(xb, wqb, wkb, wvb, Qb, Kb, VTb);

  attn_fused<<<4096, 64, 0, stream>>>(Qb, Kb, VTb, ctx);

  gemm_out<<<dim3(MT / 128, E_ / 128), 256, 0, stream>>>(ctx, wob, out, bout, (int)MT, E_, E_);
}

// Round 7
// 257.520 us; speedup vs baseline: 1.2280x; 1.2280x over previous
//
#include <hip/hip_runtime.h>
#include <hip/hip_bf16.h>
#include <stdint.h>
#include <math.h>

#define B_ 4
#define T_ 2048
#define E_ 1024
#define H_ 16
#define D_ 64

typedef __attribute__((ext_vector_type(8))) short short8;
typedef __attribute__((ext_vector_type(4))) float f32x4;

#define MFMA_BF16(a, b, c) __builtin_amdgcn_mfma_f32_16x16x32_bf16((a), (b), (c), 0, 0, 0)

__device__ __forceinline__ unsigned short f2bf(float f) {
  union { float f; unsigned u; } v; v.f = f;
  unsigned r = v.u + 0x7FFFu + ((v.u >> 16) & 1u);  // RNE
  return (unsigned short)(r >> 16);
}

#define GLOAD_LDS16(g, l)                                                        \
  __builtin_amdgcn_global_load_lds((const __attribute__((address_space(1))) void*)(g), \
                                   (__attribute__((address_space(3))) void*)(l), 16, 0, 0)

// ---------------- fp32 -> bf16 convert (vectorized) ----------------
__global__ __launch_bounds__(256) void cvt_f32_bf16(const float* __restrict__ in,
                                                    unsigned short* __restrict__ out,
                                                    int n8) {
  int i = blockIdx.x * blockDim.x + threadIdx.x;
  if (i >= n8) return;
  const float4* p = (const float4*)(in + (size_t)i * 8);
  float4 a = p[0], b = p[1];
  short8 r;
  r[0] = (short)f2bf(a.x); r[1] = (short)f2bf(a.y);
  r[2] = (short)f2bf(a.z); r[3] = (short)f2bf(a.w);
  r[4] = (short)f2bf(b.x); r[5] = (short)f2bf(b.y);
  r[6] = (short)f2bf(b.z); r[7] = (short)f2bf(b.w);
  *(short8*)(out + (size_t)i * 8) = r;
}

// 4 weight matrices in one launch (dest regions contiguous in ws)
__global__ __launch_bounds__(256) void cvt_w4(const float* __restrict__ w0,
                                              const float* __restrict__ w1,
                                              const float* __restrict__ w2,
                                              const float* __restrict__ w3,
                                              unsigned short* __restrict__ out) {
  int i = blockIdx.x * blockDim.x + threadIdx.x;  // one per 8 elems
  int which = i >> 17;                            // WE/8 = 2^17
  int off = i & 131071;
  const float* src = (which == 0) ? w0 : (which == 1) ? w1 : (which == 2) ? w2 : w3;
  const float4* p = (const float4*)(src + (size_t)off * 8);
  float4 a = p[0], b = p[1];
  short8 r;
  r[0] = (short)f2bf(a.x); r[1] = (short)f2bf(a.y);
  r[2] = (short)f2bf(a.z); r[3] = (short)f2bf(a.w);
  r[4] = (short)f2bf(b.x); r[5] = (short)f2bf(b.y);
  r[6] = (short)f2bf(b.z); r[7] = (short)f2bf(b.w);
  *(short8*)(out + ((size_t)which << 20) + (size_t)off * 8) = r;
}

// ---------------- fused QKV GEMM: C = x * W^T for W in {Wq,Wk,Wv} -------------
__global__ __launch_bounds__(256) void gemm_qkv(const unsigned short* __restrict__ A,
                                                const unsigned short* __restrict__ Wq,
                                                const unsigned short* __restrict__ Wk,
                                                const unsigned short* __restrict__ Wv,
                                                unsigned short* __restrict__ Qo,
                                                unsigned short* __restrict__ Ko,
                                                unsigned short* __restrict__ Vo) {
  __shared__ __align__(16) unsigned short Ab[128 * 64];
  __shared__ __align__(16) unsigned short Bb[128 * 64];
  const int K = E_;
  const int tid = threadIdx.x;
  const int wid = tid >> 6;
  const int lr = tid & 15;
  const int lk = (tid >> 4) & 3;
  const int wr = wid >> 1, wc = wid & 1;
  const int m0 = blockIdx.x * 128;
  const int sel = blockIdx.y >> 3;
  const int n0 = (blockIdx.y & 7) * 128;
  const unsigned short* Bm = (sel == 0) ? Wq : (sel == 1) ? Wk : Wv;
  unsigned short* outp = (sel == 0) ? Qo : (sel == 1) ? Ko : Vo;

  f32x4 acc[4][4] = {};

  for (int k0 = 0; k0 < K; k0 += 64) {
    __syncthreads();
#pragma unroll
    for (int pass = 0; pass < 4; ++pass) {
      int chunk = pass * 256 + tid;
      int row = chunk >> 3, inner = chunk & 7;
      const unsigned short* ga = A + (size_t)(m0 + row) * K + k0 + inner * 8;
      const unsigned short* gb = Bm + (size_t)(n0 + row) * K + k0 + inner * 8;
      unsigned short* la = Ab + (size_t)(pass * 256 + wid * 64) * 8;
      unsigned short* lb = Bb + (size_t)(pass * 256 + wid * 64) * 8;
      GLOAD_LDS16(ga, la);
      GLOAD_LDS16(gb, lb);
    }
    __syncthreads();
#pragma unroll
    for (int kk = 0; kk < 2; ++kk) {
      short8 af[4], bf[4];
#pragma unroll
      for (int mi = 0; mi < 4; ++mi)
        af[mi] = *(const short8*)&Ab[(wr * 64 + mi * 16 + lr) * 64 + kk * 32 + lk * 8];
#pragma unroll
      for (int ni = 0; ni < 4; ++ni)
        bf[ni] = *(const short8*)&Bb[(wc * 64 + ni * 16 + lr) * 64 + kk * 32 + lk * 8];
#pragma unroll
      for (int mi = 0; mi < 4; ++mi)
#pragma unroll
        for (int ni = 0; ni < 4; ++ni)
          acc[mi][ni] = MFMA_BF16(af[mi], bf[ni], acc[mi][ni]);
    }
  }

#pragma unroll
  for (int mi = 0; mi < 4; ++mi)
#pragma unroll
    for (int ni = 0; ni < 4; ++ni)
#pragma unroll
      for (int r = 0; r < 4; ++r) {
        int row = m0 + wr * 64 + mi * 16 + lk * 4 + r;
        int col = n0 + wc * 64 + ni * 16 + lr;
        int b = row >> 11, t = row & (T_ - 1), h = col >> 6, d = col & (D_ - 1);
        outp[(((size_t)(b * H_ + h)) * T_ + t) * D_ + d] = f2bf(acc[mi][ni][r]);
      }
}

// ---------------- out-proj GEMM: fp32 out + bias ----------------
__global__ __launch_bounds__(256) void gemm_out(const unsigned short* __restrict__ A,
                                                const unsigned short* __restrict__ Bm,
                                                float* __restrict__ outp,
                                                const float* __restrict__ bias,
                                                int M, int N, int K) {
  __shared__ __align__(16) unsigned short Ab[128 * 64];
  __shared__ __align__(16) unsigned short Bb[128 * 64];
  const int tid = threadIdx.x;
  const int wid = tid >> 6;
  const int lr = tid & 15;
  const int lk = (tid >> 4) & 3;
  const int wr = wid >> 1, wc = wid & 1;
  const int m0 = blockIdx.x * 128, n0 = blockIdx.y * 128;

  f32x4 acc[4][4] = {};

  for (int k0 = 0; k0 < K; k0 += 64) {
    __syncthreads();
#pragma unroll
    for (int pass = 0; pass < 4; ++pass) {
      int chunk = pass * 256 + tid;
      int row = chunk >> 3, inner = chunk & 7;
      const unsigned short* ga = A + (size_t)(m0 + row) * K + k0 + inner * 8;
      const unsigned short* gb = Bm + (size_t)(n0 + row) * K + k0 + inner * 8;
      unsigned short* la = Ab + (size_t)(pass * 256 + wid * 64) * 8;
      unsigned short* lb = Bb + (size_t)(pass * 256 + wid * 64) * 8;
      GLOAD_LDS16(ga, la);
      GLOAD_LDS16(gb, lb);
    }
    __syncthreads();
#pragma unroll
    for (int kk = 0; kk < 2; ++kk) {
      short8 af[4], bf[4];
#pragma unroll
      for (int mi = 0; mi < 4; ++mi)
        af[mi] = *(const short8*)&Ab[(wr * 64 + mi * 16 + lr) * 64 + kk * 32 + lk * 8];
#pragma unroll
      for (int ni = 0; ni < 4; ++ni)
        bf[ni] = *(const short8*)&Bb[(wc * 64 + ni * 16 + lr) * 64 + kk * 32 + lk * 8];
#pragma unroll
      for (int mi = 0; mi < 4; ++mi)
#pragma unroll
        for (int ni = 0; ni < 4; ++ni)
          acc[mi][ni] = MFMA_BF16(af[mi], bf[ni], acc[mi][ni]);
    }
  }

#pragma unroll
  for (int mi = 0; mi < 4; ++mi)
#pragma unroll
    for (int ni = 0; ni < 4; ++ni)
#pragma unroll
      for (int r = 0; r < 4; ++r) {
        int row = m0 + wr * 64 + mi * 16 + lk * 4 + r;
        int col = n0 + wc * 64 + ni * 16 + lr;
        outp[(size_t)row * N + col] = acc[mi][ni][r] + bias[col];
      }
}

// ---------------- V transpose: [BH][T][D] -> [BH][D][T] ----------------
__global__ __launch_bounds__(256) void transpose_v(const unsigned short* __restrict__ V,
                                                   unsigned short* __restrict__ VT) {
  const int lane = threadIdx.x & 63;
  const int w = threadIdx.x >> 6;
  const int tb = blockIdx.x * 64;
  const int bh = blockIdx.y;
  const unsigned short* Vh = V + (size_t)bh * T_ * D_;
  unsigned short* Vo = VT + (size_t)bh * T_ * D_;
  short8 v0, v1;
#pragma unroll
  for (int j = 0; j < 8; ++j)
    v0[j] = (short)Vh[(size_t)(tb + w * 16 + j) * D_ + lane];
#pragma unroll
  for (int j = 0; j < 8; ++j)
    v1[j] = (short)Vh[(size_t)(tb + w * 16 + 8 + j) * D_ + lane];
  *(short8*)&Vo[(size_t)lane * T_ + tb + w * 16] = v0;
  *(short8*)&Vo[(size_t)lane * T_ + tb + w * 16 + 8] = v1;
}

// ---------------- fused causal flash attention (swapped QK^T) ----------------
// 2048 blocks x 64 thr: each wave runs chunk pair (63-p, p) => uniform 33
// tiles/block (perfect balance, no tail). K register-double-buffered: V loads
// issue FIRST, then next-tile K prefetch, so PV's vmcnt leaves the K prefetch
// in flight (vmcnt is issue-ordered). P round-trips via stride-144B LDS rows
// (2-way bank aliasing = free).
__device__ __forceinline__ void run_chunk(int chunk,
                                          const unsigned short* __restrict__ Qh,
                                          const unsigned short* __restrict__ Kh,
                                          const unsigned short* __restrict__ Vh,
                                          unsigned short* __restrict__ ctx,
                                          int b, int h2, char* Pb, int lane) {
  const int lr = lane & 15;
  const int lk = lane >> 4;
  const int q0 = chunk * 32;
  const float SC = 0.125f * 1.44269504089f;  // 1/sqrt(D) * log2(e)

  short8 vones;
#pragma unroll
  for (int j = 0; j < 8; ++j) vones[j] = (short)0x3F80;  // bf16 1.0

  // Q as B-operand: col=q=lr, k=d
  short8 qf[2][2];
#pragma unroll
  for (int a = 0; a < 2; ++a)
#pragma unroll
    for (int kb = 0; kb < 2; ++kb)
      qf[a][kb] = *(const short8*)&Qh[(size_t)(q0 + a * 16 + lr) * D_ + kb * 32 + lk * 8];

  f32x4 o[2][4] = {};
  f32x4 lsum[2] = {};
  float mrun[2] = {-1e30f, -1e30f};

  const int nt = (q0 >> 6) + 1;
  const int ql0 = q0 & 63;

  auto loadK = [&](short8(&kf)[2][4], int t) {
    const unsigned short* Kt = Kh + (size_t)t * 64 * D_;
#pragma unroll
    for (int kb = 0; kb < 2; ++kb)
#pragma unroll
      for (int n = 0; n < 4; ++n)
        kf[kb][n] = *(const short8*)&Kt[(size_t)(n * 16 + lr) * D_ + kb * 32 + lk * 8];
  };

  auto tile = [&](short8(&kfc)[2][4], short8(&kfn)[2][4], int kvt) {
    const unsigned short* Vtt = Vh + (size_t)kvt * 64;

    // V fragments FIRST (PV's vmcnt then doesn't cover the K prefetch)
    short8 vreg[2][4];
#pragma unroll
    for (int kb = 0; kb < 2; ++kb)
#pragma unroll
      for (int nd = 0; nd < 4; ++nd)
        vreg[kb][nd] = *(const short8*)&Vtt[(size_t)(nd * 16 + lr) * T_ + kb * 32 + lk * 8];

    // K prefetch for next tile (clamped; redundant on last tile, harmless)
    int tn = kvt + 1 < nt ? kvt + 1 : nt - 1;
    loadK(kfn, tn);

    // S^T = K Q^T : row=kv (n*16+lk*4+r), col=q (lr)
    f32x4 st[2][4] = {};
#pragma unroll
    for (int kb = 0; kb < 2; ++kb)
#pragma unroll
      for (int a = 0; a < 2; ++a)
#pragma unroll
        for (int n = 0; n < 4; ++n)
          st[a][n] = MFMA_BF16(kfc[kb][n], qf[a][kb], st[a][n]);

    if (kvt == nt - 1) {  // diagonal tile: mask kv_local > q_local
#pragma unroll
      for (int a = 0; a < 2; ++a)
#pragma unroll
        for (int n = 0; n < 4; ++n)
#pragma unroll
          for (int r = 0; r < 4; ++r)
            if (n * 16 + lk * 4 + r > ql0 + a * 16 + lr) st[a][n][r] = -3e38f;
    }

    // row max (in-lane tree + 2 shuffles)
    float pm[2];
#pragma unroll
    for (int a = 0; a < 2; ++a) {
      float m0 = fmaxf(fmaxf(st[a][0][0], st[a][1][0]), fmaxf(st[a][2][0], st[a][3][0]));
      float m1 = fmaxf(fmaxf(st[a][0][1], st[a][1][1]), fmaxf(st[a][2][1], st[a][3][1]));
      float m2 = fmaxf(fmaxf(st[a][0][2], st[a][1][2]), fmaxf(st[a][2][2], st[a][3][2]));
      float m3 = fmaxf(fmaxf(st[a][0][3], st[a][1][3]), fmaxf(st[a][2][3], st[a][3][3]));
      float mx = fmaxf(fmaxf(m0, m1), fmaxf(m2, m3));
      mx = fmaxf(mx, __shfl_xor(mx, 16));
      mx = fmaxf(mx, __shfl_xor(mx, 32));
      pm[a] = mx * SC;
    }
    float need = fmaxf(pm[0] - mrun[0], pm[1] - mrun[1]);

    if (__any(need > 8.f)) {  // defer-max rescale (rare)
#pragma unroll
      for (int a = 0; a < 2; ++a) {
        float mnew = fmaxf(mrun[a], pm[a]);
        float sc = exp2f(mrun[a] - mnew);
        mrun[a] = mnew;
#pragma unroll
        for (int r = 0; r < 4; ++r) {
          float sco = __shfl(sc, (lane & 48) | (lk * 4 + r));
          lsum[a][r] *= sco;
#pragma unroll
          for (int nd = 0; nd < 4; ++nd) o[a][nd][r] *= sco;
        }
      }
    }

    // P = exp2(S*SC - m), packed bf16x4 -> LDS (8x ds_write_b64, stride 144)
#pragma unroll
    for (int a = 0; a < 2; ++a)
#pragma unroll
      for (int n = 0; n < 4; ++n) {
        float2 p01, p23;
        p01.x = exp2f(fmaf(st[a][n][0], SC, -mrun[a]));
        p01.y = exp2f(fmaf(st[a][n][1], SC, -mrun[a]));
        p23.x = exp2f(fmaf(st[a][n][2], SC, -mrun[a]));
        p23.y = exp2f(fmaf(st[a][n][3], SC, -mrun[a]));
        __hip_bfloat162 b01 = __float22bfloat162_rn(p01);
        __hip_bfloat162 b23 = __float22bfloat162_rn(p23);
        uint2 w;
        w.x = *(unsigned*)&b01;
        w.y = *(unsigned*)&b23;
        *(uint2*)(Pb + (a * 16 + lr) * 144 + n * 32 + lk * 8) = w;
      }
    asm volatile("s_waitcnt lgkmcnt(0)" ::: "memory");
    __builtin_amdgcn_sched_barrier(0);

    // O += P V ; lsum += P * ones
#pragma unroll
    for (int kb = 0; kb < 2; ++kb) {
      short8 pf0 = *(const short8*)(Pb + (0 * 16 + lr) * 144 + kb * 64 + lk * 16);
      short8 pf1 = *(const short8*)(Pb + (1 * 16 + lr) * 144 + kb * 64 + lk * 16);
#pragma unroll
      for (int nd = 0; nd < 4; ++nd) {
        o[0][nd] = MFMA_BF16(pf0, vreg[kb][nd], o[0][nd]);
        o[1][nd] = MFMA_BF16(pf1, vreg[kb][nd], o[1][nd]);
      }
      lsum[0] = MFMA_BF16(pf0, vones, lsum[0]);
      lsum[1] = MFMA_BF16(pf1, vones, lsum[1]);
    }
  };

  short8 kf0[2][4], kf1[2][4];
  loadK(kf0, 0);
  int kvt = 0;
  while (true) {
    tile(kf0, kf1, kvt);
    if (++kvt >= nt) break;
    tile(kf1, kf0, kvt);
    if (++kvt >= nt) break;
  }

#pragma unroll
  for (int a = 0; a < 2; ++a)
#pragma unroll
    for (int r = 0; r < 4; ++r) {
      float inv = 1.0f / lsum[a][r];
      int t = q0 + a * 16 + lk * 4 + r;
#pragma unroll
      for (int nd = 0; nd < 4; ++nd)
        ctx[((size_t)b * T_ + t) * E_ + h2 * D_ + nd * 16 + lr] = f2bf(o[a][nd][r] * inv);
    }
}

__global__ __launch_bounds__(64) void attn_fused(const unsigned short* __restrict__ Q,
                                                 const unsigned short* __restrict__ K,
                                                 const unsigned short* __restrict__ VT,
                                                 unsigned short* __restrict__ ctx) {
  __shared__ __align__(16) unsigned short Pl[32 * 72];  // 32 rows x 144 B
  const int lane = threadIdx.x & 63;

  // XCD swizzle: 8 heads/XCD. 2048 blocks = 8 xcd x 8 heads x 32 pairs.
  const int bid = blockIdx.x;
  const int xcd = bid & 7;
  const int p = bid >> 3;        // 0..255 per XCD
  const int bh = xcd * 8 + (p & 7);
  const int pair = p >> 3;       // 0..31

  const unsigned short* Qh = Q + (size_t)bh * T_ * D_;
  const unsigned short* Kh = K + (size_t)bh * T_ * D_;
  const unsigned short* Vh = VT + (size_t)bh * T_ * D_;  // [D][T]
  const int b = bh >> 4, h2 = bh & 15;

  run_chunk(63 - pair, Qh, Kh, Vh, ctx, b, h2, (char*)Pl, lane);
  run_chunk(pair, Qh, Kh, Vh, ctx, b, h2, (char*)Pl, lane);
}

// ---------------- launcher ----------------
extern "C" void kernel_launch(void* const* d_in, const int* in_sizes, int n_in,
                              void* d_out, int out_size, void* d_ws, size_t ws_size,
                              hipStream_t stream) {
  const float* x    = (const float*)d_in[0];
  const float* Wq   = (const float*)d_in[1];
  const float* Wk   = (const float*)d_in[2];
  const float* Wv   = (const float*)d_in[3];
  const float* Wout = (const float*)d_in[4];
  const float* bout = (const float*)d_in[5];
  float* out = (float*)d_out;

  const size_t MT = (size_t)B_ * T_;      // 8192
  const size_t XE = MT * E_;              // 8,388,608
  const size_t WE = (size_t)E_ * E_;      // 1,048,576

  size_t need = (XE * 5 + WE * 4) * sizeof(unsigned short);
  if (ws_size < need) return;

  unsigned short* xb  = (unsigned short*)d_ws;
  unsigned short* wqb = xb + XE;
  unsigned short* wkb = wqb + WE;
  unsigned short* wvb = wkb + WE;
  unsigned short* wob = wvb + WE;
  unsigned short* Qb  = wob + WE;
  unsigned short* Kb  = Qb + XE;
  unsigned short* VTb = Kb + XE;
  unsigned short* ctx = VTb + XE;

  cvt_f32_bf16<<<(int)(XE / 8 / 256), 256, 0, stream>>>(x, xb, (int)(XE / 8));
  cvt_w4<<<2048, 256, 0, stream>>>(Wq, Wk, Wv, Wout, wqb);

  gemm_qkv<<<dim3(MT / 128, 24), 256, 0, stream>>>(xb, wqb, wkb, wvb, Qb, Kb, ctx);  // V -> ctx (temp)

  transpose_v<<<dim3(T_ / 64, B_ * H_), 256, 0, stream>>>(ctx, VTb);

  attn_fused<<<2048, 64, 0, stream>>>(Qb, Kb, VTb, ctx);

  gemm_out<<<dim3(MT / 128, E_ / 128), 256, 0, stream>>>(ctx, wob, out, bout, (int)MT, E_, E_);
}